// Round 7
// baseline (87.370 us; speedup 1.0000x reference)
//
#include <hip/hip_runtime.h>

typedef __attribute__((ext_vector_type(4))) float f32x4;
typedef __attribute__((ext_vector_type(16))) float f32x16;
typedef __attribute__((ext_vector_type(8))) short short8;
typedef __attribute__((ext_vector_type(4))) int i32x4;

#define S_LEN 4096
#define DM    1024
#define NH    16
#define DH    64
#define WIN   256

__device__ inline unsigned short f2b(float f) {
  unsigned int x = __float_as_uint(f);
  unsigned int r = (x + 0x7fffu + ((x >> 16) & 1u)) >> 16;
  return (unsigned short)r;
}

__device__ inline void gload_lds16(const void* g, void* l) {
  __builtin_amdgcn_global_load_lds(
      (const __attribute__((address_space(1))) void*)g,
      (__attribute__((address_space(3))) void*)l, 16, 0, 0);
}

// ---------------------------------------------------------------------------
// Convert X and the 4 weight matrices f32 -> bf16.
// ---------------------------------------------------------------------------
__global__ __launch_bounds__(256) void cvt_all(
    const float* __restrict__ x,
    const float* __restrict__ qw, const float* __restrict__ kw,
    const float* __restrict__ vw, const float* __restrict__ ow,
    unsigned short* __restrict__ Xb, unsigned short* __restrict__ Wb)
{
  const int y = blockIdx.y;
  const float* src;
  unsigned short* dst;
  int n8;
  if (y == 0) { src = x; dst = Xb; n8 = (S_LEN * DM) / 8; }
  else {
    src = (y == 1) ? qw : (y == 2) ? kw : (y == 3) ? vw : ow;
    dst = Wb + (size_t)(y - 1) * DM * DM;
    n8 = (DM * DM) / 8;
  }
  const int i = blockIdx.x * 256 + threadIdx.x;
  if (i >= n8) return;
  const float4* s4 = (const float4*)src + (size_t)i * 2;
  float4 a = s4[0], b = s4[1];
  short8 v;
  v[0] = f2b(a.x); v[1] = f2b(a.y); v[2] = f2b(a.z); v[3] = f2b(a.w);
  v[4] = f2b(b.x); v[5] = f2b(b.y); v[6] = f2b(b.z); v[7] = f2b(b.w);
  *(short8*)(dst + (size_t)i * 8) = v;
}

// ---------------------------------------------------------------------------
// Depth-2 pipelined GEMM: C = A x B^T + bias.  BK=32, FOUR LDS buffers,
// stage-distance 2, counted vmcnt(8) (tiles t+1,t+2 stay in flight while
// tile t is guaranteed landed), ONE barrier per K-tile.  At BK=32 the LDS
// row stride is 64B (16 dwords), so b128 reads are bank-uniform with a
// plain linear layout — no swizzle needed.
// qkv: 256x256 tile, 8 waves (2x4).  out: 128x128 tile, 4 waves (2 blk/CU).
// ---------------------------------------------------------------------------
template<int BM, int BN, int NWM, int NWN, bool F32OUT>
__global__ __launch_bounds__(NWM* NWN * 64) void gemm_bt(
    const unsigned short* __restrict__ A,
    const unsigned short* __restrict__ Wb,
    const float* __restrict__ b0, const float* __restrict__ b1, const float* __restrict__ b2,
    unsigned short* __restrict__ Obf,
    float* __restrict__ Of)
{
  constexpr int THREADS = NWM * NWN * 64;
  constexpr int MR = BM / (NWM * 16);
  constexpr int NR = BN / (NWN * 16);
  constexpr int RSM = BM / NWM;
  constexpr int RSN = BN / NWN;
  constexpr int ASZ = BM * 32;            // shorts per A part
  constexpr int BUFSZ = ASZ + BN * 32;    // shorts per buffer
  static_assert((BM * 64) / (THREADS * 16) == 2, "2 A-loads per thread");
  static_assert((BN * 64) / (THREADS * 16) == 2, "2 B-loads per thread");

  const int z = blockIdx.z;
  const unsigned short* Bmat = Wb + (size_t)z * DM * DM;
  const float* bias = (z == 0) ? b0 : (z == 1) ? b1 : b2;
  unsigned short* O = Obf + (size_t)z * S_LEN * DM;

  __shared__ __align__(16) unsigned short LDS[4 * BUFSZ];
  unsigned short* buf0 = LDS;
  unsigned short* buf1 = LDS + BUFSZ;
  unsigned short* buf2 = LDS + 2 * BUFSZ;
  unsigned short* buf3 = LDS + 3 * BUFSZ;

  const int t = threadIdx.x;
  const int lane = t & 63, w = t >> 6;
  const int wm = w / NWN, wn = w % NWN;
  const int lr = lane & 15, lg = lane >> 4;
  const int m0 = blockIdx.x * BM, n0 = blockIdx.y * BN;

  // staging: load i covers rows i*(THREADS/4); thread row = t>>2, col = (t&3)*8
  const unsigned short* gA = A + (size_t)(m0 + (t >> 2)) * DM + (t & 3) * 8;
  const unsigned short* gB = Bmat + (size_t)(n0 + (t >> 2)) * DM + (t & 3) * 8;
  const int ldsOff = w * 64 * 8;          // wave-uniform short offset (lane*16B added by HW)

#define STAGE(e0_, bufp_)                                                        \
  do {                                                                           \
    gload_lds16(gA + (e0_), (bufp_) + ldsOff);                                   \
    gload_lds16(gA + (size_t)(THREADS / 4) * DM + (e0_),                         \
                (bufp_) + THREADS * 8 + ldsOff);                                 \
    gload_lds16(gB + (e0_), (bufp_) + ASZ + ldsOff);                             \
    gload_lds16(gB + (size_t)(THREADS / 4) * DM + (e0_),                         \
                (bufp_) + ASZ + THREADS * 8 + ldsOff);                           \
  } while (0)

  f32x4 acc[MR][NR];
#pragma unroll
  for (int m = 0; m < MR; ++m)
#pragma unroll
    for (int n = 0; n < NR; ++n) acc[m][n] = (f32x4){0.f, 0.f, 0.f, 0.f};

#define COMPUTE(bufp_)                                                           \
  do {                                                                           \
    short8 af[MR], bf[NR];                                                       \
    _Pragma("unroll") for (int m = 0; m < MR; ++m)                               \
      af[m] = *(const short8*)((bufp_) + (wm * RSM + m * 16 + lr) * 32 + lg * 8); \
    _Pragma("unroll") for (int n = 0; n < NR; ++n)                               \
      bf[n] = *(const short8*)((bufp_) + ASZ + (wn * RSN + n * 16 + lr) * 32 + lg * 8); \
    _Pragma("unroll") for (int m = 0; m < MR; ++m)                               \
      _Pragma("unroll") for (int n = 0; n < NR; ++n)                             \
        acc[m][n] = __builtin_amdgcn_mfma_f32_16x16x32_bf16(af[m], bf[n], acc[m][n], 0, 0, 0); \
  } while (0)

#define ITER(tt_, bufc_, bufs_)                                                  \
  do {                                                                           \
    STAGE(((tt_) + 2) * 32, bufs_);                                              \
    asm volatile("s_waitcnt vmcnt(8)" ::: "memory");                             \
    __builtin_amdgcn_s_barrier();                                                \
    __builtin_amdgcn_sched_barrier(0);                                           \
    __builtin_amdgcn_s_setprio(1);                                               \
    COMPUTE(bufc_);                                                              \
    __builtin_amdgcn_s_setprio(0);                                               \
    __builtin_amdgcn_sched_barrier(0);                                           \
  } while (0)

#define ITER_TAIL(vm_, bufc_)                                                    \
  do {                                                                           \
    asm volatile("s_waitcnt vmcnt(" #vm_ ")" ::: "memory");                      \
    __builtin_amdgcn_s_barrier();                                                \
    __builtin_amdgcn_sched_barrier(0);                                           \
    __builtin_amdgcn_s_setprio(1);                                               \
    COMPUTE(bufc_);                                                              \
    __builtin_amdgcn_s_setprio(0);                                               \
    __builtin_amdgcn_sched_barrier(0);                                           \
  } while (0)

  // 32 K-tiles of 32.  Prologue stages tiles 0,1; loop stages t+2.
  STAGE(0, buf0);
  STAGE(32, buf1);
#pragma unroll 1
  for (int tb = 0; tb < 28; tb += 4) {
    ITER(tb + 0, buf0, buf2);
    ITER(tb + 1, buf1, buf3);
    ITER(tb + 2, buf2, buf0);
    ITER(tb + 3, buf3, buf1);
  }
  ITER(28, buf0, buf2);   // stages tile 30 -> buf2
  ITER(29, buf1, buf3);   // stages tile 31 -> buf3
  ITER_TAIL(4, buf2);     // tile 30
  ITER_TAIL(0, buf3);     // tile 31

#undef STAGE
#undef COMPUTE
#undef ITER
#undef ITER_TAIL

#pragma unroll
  for (int n = 0; n < NR; ++n) {
    const int gc = n0 + wn * RSN + n * 16 + lr;
    const float bv = bias[gc];
#pragma unroll
    for (int m = 0; m < MR; ++m) {
      const int gr0 = m0 + wm * RSM + m * 16 + lg * 4;
#pragma unroll
      for (int r = 0; r < 4; ++r) {
        const float val = acc[m][n][r] + bv;
        if (F32OUT) Of[(size_t)(gr0 + r) * DM + gc] = val;
        else        O[(size_t)(gr0 + r) * DM + gc] = f2b(val);
      }
    }
  }
}

// ---------------------------------------------------------------------------
// Sliding-window attention v2 (unchanged): 1 warp per 32 q-rows, 32x32x16
// MFMA, swapped QK^T, static-max softmax, zero barriers, K/V prefetch.
// ---------------------------------------------------------------------------
__global__ __launch_bounds__(256) void attn(
    const unsigned short* __restrict__ Q,
    const unsigned short* __restrict__ Km,
    const unsigned short* __restrict__ Vm,
    unsigned short* __restrict__ AO)
{
  const int warp = threadIdx.x >> 6;
  const int l = threadIdx.x & 63;
  const int qw0 = (blockIdx.x * 4 + warp) * 32;
  const int hD = blockIdx.y * DH;
  const int q = l & 31;
  const int hi = l >> 5;
  const int l31 = l & 31;
  const int vkey = (l & 15) * 2;
  const int vd0 = (l >> 4) * 16;

  __shared__ __align__(16) unsigned short VtS[4][2][64 * 40];
  unsigned short* vt0 = &VtS[warp][0][0];
  unsigned short* vt1 = &VtS[warp][1][0];

  short8 qf[4];
  {
    const unsigned short* qp = Q + (size_t)(qw0 + q) * DM + hD + hi * 8;
#pragma unroll
    for (int ks = 0; ks < 4; ++ks) qf[ks] = *(const short8*)(qp + ks * 16);
  }

  f32x16 o0{}, o1{};
  float lsum = 0.f;

  const int kb0 = (qw0 >= WIN) ? (qw0 - WIN) : 0;
  const int nch = (qw0 + 32 - kb0) >> 5;

  short8 kfA[4], vfA[4], kfB[4], vfB[4];

#define LOADKV(kb_, kf_, vf_)                                                    \
  do {                                                                           \
    const unsigned short* kp_ = Km + (size_t)((kb_) + l31) * DM + hD + hi * 8;   \
    (kf_)[0] = *(const short8*)kp_;                                              \
    (kf_)[1] = *(const short8*)(kp_ + 16);                                       \
    (kf_)[2] = *(const short8*)(kp_ + 32);                                       \
    (kf_)[3] = *(const short8*)(kp_ + 48);                                       \
    const unsigned short* vp_ = Vm + (size_t)((kb_) + vkey) * DM + hD + vd0;     \
    (vf_)[0] = *(const short8*)vp_;                                              \
    (vf_)[1] = *(const short8*)(vp_ + 8);                                        \
    (vf_)[2] = *(const short8*)(vp_ + DM);                                       \
    (vf_)[3] = *(const short8*)(vp_ + DM + 8);                                   \
  } while (0)

#define PROCESS(kb_, kf_, vf_, vt_)                                             \
  do {                                                                          \
    const int kbv = (kb_);                                                      \
    _Pragma("unroll") for (int j = 0; j < 16; ++j) {                            \
      unsigned int wv = (unsigned int)(unsigned short)(vf_)[j >> 3][j & 7]      \
          | ((unsigned int)(unsigned short)(vf_)[2 + (j >> 3)][j & 7] << 16);   \
      *(unsigned int*)((vt_) + (vd0 + j) * 40 + vkey) = wv;                     \
    }                                                                           \
    f32x16 s{};                                                                 \
    _Pragma("unroll") for (int ks = 0; ks < 4; ++ks)                            \
      s = __builtin_amdgcn_mfma_f32_32x32x16_bf16((kf_)[ks], qf[ks], s, 0, 0, 0); \
    float p[16];                                                                \
    const bool isEdge = (kbv >= qw0) || (kbv + WIN - 32 < qw0);                 \
    if (isEdge) {                                                               \
      _Pragma("unroll") for (int r = 0; r < 16; ++r) {                          \
        const int key = kbv + (r & 3) + 8 * (r >> 2) + 4 * hi;                  \
        const int qg = qw0 + q;                                                 \
        const bool valid = (key <= qg) && (qg - key < WIN);                     \
        p[r] = __expf(valid ? s[r] * 0.125f : -1e30f);                          \
        lsum += p[r];                                                           \
      }                                                                         \
    } else {                                                                    \
      _Pragma("unroll") for (int r = 0; r < 16; ++r) {                          \
        p[r] = __expf(s[r] * 0.125f);                                           \
        lsum += p[r];                                                           \
      }                                                                         \
    }                                                                           \
    unsigned int u[8];                                                          \
    _Pragma("unroll") for (int t2 = 0; t2 < 4; ++t2) {                          \
      u[2 * t2]     = (unsigned int)f2b(p[4 * t2])     | ((unsigned int)f2b(p[4 * t2 + 1]) << 16); \
      u[2 * t2 + 1] = (unsigned int)f2b(p[4 * t2 + 2]) | ((unsigned int)f2b(p[4 * t2 + 3]) << 16); \
    }                                                                           \
    const unsigned int sd0 = hi ? u[0] : u[2], sd1 = hi ? u[1] : u[3];          \
    const unsigned int rc0 = __shfl_xor(sd0, 32, 64), rc1 = __shfl_xor(sd1, 32, 64); \
    const unsigned int sd2 = hi ? u[4] : u[6], sd3 = hi ? u[5] : u[7];          \
    const unsigned int rc2 = __shfl_xor(sd2, 32, 64), rc3 = __shfl_xor(sd3, 32, 64); \
    i32x4 pw0, pw1;                                                             \
    pw0[0] = hi ? rc0 : u[0]; pw0[1] = hi ? rc1 : u[1];                         \
    pw0[2] = hi ? u[2] : rc0; pw0[3] = hi ? u[3] : rc1;                         \
    pw1[0] = hi ? rc2 : u[4]; pw1[1] = hi ? rc3 : u[5];                         \
    pw1[2] = hi ? u[6] : rc2; pw1[3] = hi ? u[7] : rc3;                         \
    const short8 pf0 = *(const short8*)&pw0;                                    \
    const short8 pf1 = *(const short8*)&pw1;                                    \
    const short8 a00 = *(const short8*)((vt_) + l31 * 40 + hi * 8);             \
    const short8 a01 = *(const short8*)((vt_) + l31 * 40 + 16 + hi * 8);        \
    const short8 a10 = *(const short8*)((vt_) + (32 + l31) * 40 + hi * 8);      \
    const short8 a11 = *(const short8*)((vt_) + (32 + l31) * 40 + 16 + hi * 8); \
    o0 = __builtin_amdgcn_mfma_f32_32x32x16_bf16(a00, pf0, o0, 0, 0, 0);        \
    o0 = __builtin_amdgcn_mfma_f32_32x32x16_bf16(a01, pf1, o0, 0, 0, 0);        \
    o1 = __builtin_amdgcn_mfma_f32_32x32x16_bf16(a10, pf0, o1, 0, 0, 0);        \
    o1 = __builtin_amdgcn_mfma_f32_32x32x16_bf16(a11, pf1, o1, 0, 0, 0);        \
  } while (0)

  LOADKV(kb0, kfA, vfA);
  int c = 0;
#pragma unroll 1
  for (; c + 2 <= nch; c += 2) {
    const int kb = kb0 + c * 32;
    LOADKV(kb + 32, kfB, vfB);
    PROCESS(kb, kfA, vfA, vt0);
    if (c + 2 < nch) LOADKV(kb + 64, kfA, vfA);
    PROCESS(kb + 32, kfB, vfB, vt1);
  }
  if (c < nch) PROCESS(kb0 + c * 32, kfA, vfA, vt0);

#undef LOADKV
#undef PROCESS

  lsum += __shfl_xor(lsum, 32, 64);
  const float inv = 1.f / lsum;
  unsigned short* aop = AO + (size_t)(qw0 + q) * DM + hD;
#pragma unroll
  for (int t2 = 0; t2 < 4; ++t2) {
    uint2 st;
    st.x = (unsigned int)f2b(o0[4 * t2] * inv)     | ((unsigned int)f2b(o0[4 * t2 + 1] * inv) << 16);
    st.y = (unsigned int)f2b(o0[4 * t2 + 2] * inv) | ((unsigned int)f2b(o0[4 * t2 + 3] * inv) << 16);
    *(uint2*)(aop + 8 * t2 + 4 * hi) = st;
    uint2 st2;
    st2.x = (unsigned int)f2b(o1[4 * t2] * inv)     | ((unsigned int)f2b(o1[4 * t2 + 1] * inv) << 16);
    st2.y = (unsigned int)f2b(o1[4 * t2 + 2] * inv) | ((unsigned int)f2b(o1[4 * t2 + 3] * inv) << 16);
    *(uint2*)(aop + 32 + 8 * t2 + 4 * hi) = st2;
  }
}

// ---------------------------------------------------------------------------
extern "C" void kernel_launch(void* const* d_in, const int* in_sizes, int n_in,
                              void* d_out, int out_size, void* d_ws, size_t ws_size,
                              hipStream_t stream) {
  const float* x  = (const float*)d_in[0];
  const float* qw = (const float*)d_in[1];
  const float* qb = (const float*)d_in[2];
  const float* kw = (const float*)d_in[3];
  const float* kb = (const float*)d_in[4];
  const float* vw = (const float*)d_in[5];
  const float* vb = (const float*)d_in[6];
  const float* ow = (const float*)d_in[7];
  const float* ob = (const float*)d_in[8];

  const size_t SD = (size_t)S_LEN * DM;
  unsigned short* Qb  = (unsigned short*)d_ws;
  unsigned short* Kb  = Qb + SD;
  unsigned short* Vb  = Kb + SD;
  unsigned short* AOb = Vb + SD;
  unsigned short* Xb  = AOb + SD;
  unsigned short* Wcv = Xb + SD;

  cvt_all<<<dim3(2048, 5), 256, 0, stream>>>(x, qw, kw, vw, ow, Xb, Wcv);
  gemm_bt<256, 256, 2, 4, false><<<dim3(16, 4, 3), 512, 0, stream>>>(
      Xb, Wcv, qb, kb, vb, Qb, nullptr);
  attn<<<dim3(S_LEN / 128, NH), 256, 0, stream>>>(Qb, Kb, Vb, AOb);
  gemm_bt<128, 128, 2, 2, true><<<dim3(32, 8, 1), 256, 0, stream>>>(
      AOb, Wcv + (size_t)3 * DM * DM, ob, ob, ob, nullptr, (float*)d_out);
}